// Round 13
// baseline (38.353 us; speedup 1.0000x reference)
//
#include <hip/hip_runtime.h>
#include <math.h>

#define T 16
#define A 8
#define H 128
#define E 32
#define G (4*H)   // 512 gate rows per LSTM

// d_ws layout (bytes):
//   [0, 128K)          W_hh_a as f16, chunk-major: h8t at (c*512 + r)*16
//   [128K, 256K)       W_hh_c same
//   [256K, 272K)       accx_a f16 [t*512 + r]
//   [272K, 288K)       accx_c f16 [t*512 + r]
#define WS_WHH(L)   ((size_t)(L) * 131072u)
#define WS_ACCX(L)  (262144u + (size_t)(L) * 16384u)

typedef _Float16 h2t __attribute__((ext_vector_type(2)));
typedef _Float16 h8t __attribute__((ext_vector_type(8)));

__device__ __forceinline__ float sigmoidf_(float x) {
    return 1.0f / (1.0f + __expf(-x));               // safe at both extremes
}
__device__ __forceinline__ float tanhf_(float x) {
    return 1.0f - 2.0f / (1.0f + __expf(2.0f * x));  // safe at both extremes
}

#if __has_builtin(__builtin_amdgcn_fdot2)
#define DOT2(a, b, c) __builtin_amdgcn_fdot2((a), (b), (c), false)
#else
__device__ __forceinline__ float dot2_fb(h2t a, h2t b, float c) {
    return fmaf((float)a[0], (float)b[0], fmaf((float)a[1], (float)b[1], c));
}
#define DOT2(a, b, c) dot2_fb((a), (b), (c))
#endif

#define RPT16(M) M(0) M(1) M(2) M(3) M(4) M(5) M(6) M(7) \
                 M(8) M(9) M(10) M(11) M(12) M(13) M(14) M(15)

// ---------------- kernel 1: whole-GPU prologue (cold fetch + convert) -------
__global__ __launch_bounds__(256)
void ppo_prep_kernel(const int* __restrict__ old_actions,
                     const float* __restrict__ init_input,
                     const float* __restrict__ W_ih_a, const float* __restrict__ W_hh_a,
                     const float* __restrict__ b_ih_a, const float* __restrict__ b_hh_a,
                     const float* __restrict__ W_ih_c, const float* __restrict__ W_hh_c,
                     const float* __restrict__ b_ih_c, const float* __restrict__ b_hh_c,
                     const float* __restrict__ embed,
                     char* __restrict__ ws)
{
    const int b = blockIdx.x;
    if (b < 64) {
        // ---- convert: 16384 chunks (2 LSTMs x 512 rows x 16 chunks) ----
        int tau  = b * 256 + threadIdx.x;       // [0, 16384)
        int lstm = tau >> 13;
        int i    = tau & 8191;
        int r    = i >> 4;                      // row 0..511
        int c    = i & 15;                      // chunk 0..15 (8 f32 each)
        const float* W = (lstm == 0) ? W_hh_a : W_hh_c;
        const float* src = W + r * H + c * 8;
        float4 fa = *(const float4*)(src);
        float4 fb = *(const float4*)(src + 4);
        h8t p = { (_Float16)fa.x, (_Float16)fa.y, (_Float16)fa.z, (_Float16)fa.w,
                  (_Float16)fb.x, (_Float16)fb.y, (_Float16)fb.z, (_Float16)fb.w };
        *(h8t*)(ws + WS_WHH(lstm) + (size_t)(c * 512 + r) * 16u) = p;
    } else {
        // ---- accx: 16384 dots (2 LSTMs x 16 steps x 512 rows) ----
        int tau  = (b - 64) * 256 + threadIdx.x;   // [0, 16384)
        int lstm = tau >> 13;
        int i    = tau & 8191;
        int t    = i >> 9;                      // step 0..15
        int r    = i & 511;                     // gate row 0..511
        const float* W_ih = (lstm == 0) ? W_ih_a : W_ih_c;
        const float* b_ih = (lstm == 0) ? b_ih_a : b_ih_c;
        const float* b_hh = (lstm == 0) ? b_hh_a : b_hh_c;
        const float* xp = (t == 0) ? init_input
                                   : embed + ((t - 1) * A + old_actions[t - 1]) * E;
        const float* wr = W_ih + r * E;
        float s0 = 0.f, s1 = 0.f, s2 = 0.f, s3 = 0.f;
        #pragma unroll
        for (int e = 0; e < E; e += 4) {
            float4 wv = *(const float4*)(wr + e);
            float4 xv = *(const float4*)(xp + e);
            s0 = fmaf(wv.x, xv.x, s0); s1 = fmaf(wv.y, xv.y, s1);
            s2 = fmaf(wv.z, xv.z, s2); s3 = fmaf(wv.w, xv.w, s3);
        }
        float acc = b_ih[r] + b_hh[r] + ((s0 + s1) + (s2 + s3));
        *(_Float16*)(ws + WS_ACCX(lstm) + (size_t)(t * 512 + r) * 2u) = (_Float16)acc;
    }
}

// ---------------- kernel 2: serial recurrence + SELF-TIMING dummy loop ------
// Identical to the 27.9us champion (R9), plus a second, independent 16-step
// dummy recurrence (h16b, c2; same dots/LDS/barriers) whose result is kept
// live via asm. dur - 27.9 ~= cost of one full step loop.
__global__ __attribute__((amdgpu_flat_work_group_size(512, 512),
                          amdgpu_waves_per_eu(2, 2)))
void ppo_ctrl_kernel_x2loop(const int* __restrict__ old_actions,
                     const float* __restrict__ heads_W, const float* __restrict__ heads_b,
                     const float* __restrict__ critic_W, const float* __restrict__ critic_b,
                     const char* __restrict__ ws,
                     float* __restrict__ out)
{
    const int tid  = threadIdx.x;
    const int lane = tid & 63;
    const int wv   = tid >> 6;          // 8 waves
    const int lstm = blockIdx.x;        // 0 = actor, 1 = critic
    const bool actor = (lstm == 0);

    __shared__ __align__(16) float gates_s[G];       // 2 KB
    __shared__ __align__(16) _Float16 h16[H];        // 256 B
    __shared__ __align__(16) _Float16 h16b[H];       // 256 B (dummy loop)
    __shared__ __align__(16) _Float16 hhist[T][H];   // 4 KB

    if (tid < H) { h16[tid] = (_Float16)0.0f; h16b[tid] = (_Float16)0.0f; }

    // ---- stage W_hh row (f16) -> 16 pinned h8t regs; fully coalesced ----
    const char* wbase = ws + WS_WHH(lstm);
#define LOADW(i) h8t w##i = *(const h8t*)(wbase + (size_t)((i) * 512 + tid) * 16u); \
        asm volatile("" : "+v"(w##i));
    RPT16(LOADW)
#undef LOADW

    const _Float16* accg = (const _Float16*)(ws + WS_ACCX(lstm));

    float c_reg = 0.0f;                      // cell state (threads 0..127)
    const h8t* hv  = (const h8t*)h16;        // broadcast reads: conflict-free
    const h8t* hvb = (const h8t*)h16b;

    __syncthreads();                         // h16/h16b zeroed

    // ---- REAL loop: 16 sequential steps ----
    #pragma unroll 1
    for (int t = 0; t < T; ++t) {
        float axv = (float)accg[t * 512 + tid];
        float a0 = 0.f, a1 = 0.f, a2 = 0.f, a3 = 0.f;
        if (t != 0) {                        // t==0: h==0 -> dot is zero
#define MACC(i) { h8t hq = hv[i];                                          \
            a0 = DOT2(__builtin_shufflevector(w##i, w##i, 0, 1),           \
                      __builtin_shufflevector(hq,  hq,  0, 1), a0);        \
            a1 = DOT2(__builtin_shufflevector(w##i, w##i, 2, 3),           \
                      __builtin_shufflevector(hq,  hq,  2, 3), a1);        \
            a2 = DOT2(__builtin_shufflevector(w##i, w##i, 4, 5),           \
                      __builtin_shufflevector(hq,  hq,  4, 5), a2);        \
            a3 = DOT2(__builtin_shufflevector(w##i, w##i, 6, 7),           \
                      __builtin_shufflevector(hq,  hq,  6, 7), a3); }
            RPT16(MACC)
#undef MACC
        }
        gates_s[tid] = axv + ((a0 + a1) + (a2 + a3));
        __syncthreads();

        if (tid < H) {   // gate order i,f,g,o
            float gi = gates_s[tid],       gf = gates_s[tid + H];
            float gg = gates_s[tid + 2*H], go = gates_s[tid + 3*H];
            float cn = sigmoidf_(gf) * c_reg + sigmoidf_(gi) * tanhf_(gg);
            c_reg = cn;
            float hvv = sigmoidf_(go) * tanhf_(cn);
            _Float16 hf = (_Float16)hvv;
            h16[tid] = hf;
            hhist[t][tid] = hf;
        }
        __syncthreads();
    }

    // ---- DUMMY loop: identical work, independent state (self-timing A/B) ----
    float c2 = 0.0f;
    #pragma unroll 1
    for (int t = 0; t < T; ++t) {
        float axv = (float)accg[t * 512 + tid];
        float a0 = 0.f, a1 = 0.f, a2 = 0.f, a3 = 0.f;
        if (t != 0) {
#define MACC(i) { h8t hq = hvb[i];                                         \
            a0 = DOT2(__builtin_shufflevector(w##i, w##i, 0, 1),           \
                      __builtin_shufflevector(hq,  hq,  0, 1), a0);        \
            a1 = DOT2(__builtin_shufflevector(w##i, w##i, 2, 3),           \
                      __builtin_shufflevector(hq,  hq,  2, 3), a1);        \
            a2 = DOT2(__builtin_shufflevector(w##i, w##i, 4, 5),           \
                      __builtin_shufflevector(hq,  hq,  4, 5), a2);        \
            a3 = DOT2(__builtin_shufflevector(w##i, w##i, 6, 7),           \
                      __builtin_shufflevector(hq,  hq,  6, 7), a3); }
            RPT16(MACC)
#undef MACC
        }
        gates_s[tid] = axv + ((a0 + a1) + (a2 + a3));
        __syncthreads();

        if (tid < H) {
            float gi = gates_s[tid],       gf = gates_s[tid + H];
            float gg = gates_s[tid + 2*H], go = gates_s[tid + 3*H];
            float cn = sigmoidf_(gf) * c2 + sigmoidf_(gi) * tanhf_(gg);
            c2 = cn;
            float hvv = sigmoidf_(go) * tanhf_(cn);
            h16b[tid] = (_Float16)hvv;     // no hhist write in dummy
        }
        __syncthreads();
    }
    // keep the dummy loop alive (rule 17: DCE shows up as a VGPR drop)
    {
        float z = (float)h16b[tid & (H - 1)];
        asm volatile("" :: "v"(z), "v"(c2));
    }

    // ---- heads: all 16 steps in parallel (off the serial path) ----
    if (actor) {
        #pragma unroll 1
        for (int tt = wv; tt < T; tt += 8) {       // wave wv -> t = wv, wv+8
            float hA = (float)hhist[tt][lane];
            float hB = (float)hhist[tt][64 + lane];
#define LOGIT(a) float l##a; {                                            \
            const float* hw = heads_W + ((tt) * A + (a)) * H;             \
            float p = fmaf(hw[lane], hA, hw[64 + lane] * hB);             \
            p += __shfl_xor(p, 1);  p += __shfl_xor(p, 2);                \
            p += __shfl_xor(p, 4);  p += __shfl_xor(p, 8);                \
            p += __shfl_xor(p, 16); p += __shfl_xor(p, 32);               \
            l##a = p + heads_b[(tt) * A + (a)]; }
            LOGIT(0) LOGIT(1) LOGIT(2) LOGIT(3)
            LOGIT(4) LOGIT(5) LOGIT(6) LOGIT(7)
#undef LOGIT
            if (lane == 0) {
                float m = fmaxf(fmaxf(fmaxf(l0, l1), fmaxf(l2, l3)),
                                fmaxf(fmaxf(l4, l5), fmaxf(l6, l7)));
                float e0 = __expf(l0 - m), e1 = __expf(l1 - m),
                      e2 = __expf(l2 - m), e3 = __expf(l3 - m),
                      e4 = __expf(l4 - m), e5 = __expf(l5 - m),
                      e6 = __expf(l6 - m), e7 = __expf(l7 - m);
                float s = ((e0 + e1) + (e2 + e3)) + ((e4 + e5) + (e6 + e7));
                float logZ = m + __logf(s);
                int act = old_actions[tt];
                float la = (act == 0) ? l0 : (act == 1) ? l1 : (act == 2) ? l2 :
                           (act == 3) ? l3 : (act == 4) ? l4 : (act == 5) ? l5 :
                           (act == 6) ? l6 : l7;
                out[tt] = la - logZ;                       // log_probs
                float w_ = e0*(l0-logZ) + e1*(l1-logZ) + e2*(l2-logZ) + e3*(l3-logZ)
                         + e4*(l4-logZ) + e5*(l5-logZ) + e6*(l6-logZ) + e7*(l7-logZ);
                out[T + tt] = -w_ / s;                     // entropies
            }
        }
    } else {
        #pragma unroll 1
        for (int tt = wv; tt < T; tt += 8) {
            float hA = (float)hhist[tt][lane];
            float hB = (float)hhist[tt][64 + lane];
            float p = fmaf(critic_W[lane], hA, critic_W[64 + lane] * hB);
            p += __shfl_xor(p, 1);  p += __shfl_xor(p, 2);
            p += __shfl_xor(p, 4);  p += __shfl_xor(p, 8);
            p += __shfl_xor(p, 16); p += __shfl_xor(p, 32);
            if (lane == 0) out[2 * T + tt] = p + critic_b[0];   // values
        }
    }
}

extern "C" void kernel_launch(void* const* d_in, const int* in_sizes, int n_in,
                              void* d_out, int out_size, void* d_ws, size_t ws_size,
                              hipStream_t stream) {
    const int*   old_actions = (const int*)  d_in[0];
    const float* init_input  = (const float*)d_in[1];
    const float* W_ih_a      = (const float*)d_in[2];
    const float* W_hh_a      = (const float*)d_in[3];
    const float* b_ih_a      = (const float*)d_in[4];
    const float* b_hh_a      = (const float*)d_in[5];
    const float* heads_W     = (const float*)d_in[6];
    const float* heads_b     = (const float*)d_in[7];
    const float* W_ih_c      = (const float*)d_in[8];
    const float* W_hh_c      = (const float*)d_in[9];
    const float* b_ih_c      = (const float*)d_in[10];
    const float* b_hh_c      = (const float*)d_in[11];
    const float* critic_W    = (const float*)d_in[12];
    const float* critic_b    = (const float*)d_in[13];
    const float* embed       = (const float*)d_in[14];
    float* out = (float*)d_out;
    char* ws = (char*)d_ws;

    ppo_prep_kernel<<<dim3(128), dim3(256), 0, stream>>>(
        old_actions, init_input,
        W_ih_a, W_hh_a, b_ih_a, b_hh_a,
        W_ih_c, W_hh_c, b_ih_c, b_hh_c,
        embed, ws);

    ppo_ctrl_kernel_x2loop<<<dim3(2), dim3(512), 0, stream>>>(
        old_actions, heads_W, heads_b, critic_W, critic_b, ws, out);
}

// Round 15
// 31.582 us; speedup vs baseline: 1.2144x; 1.2144x over previous
//
#include <hip/hip_runtime.h>
#include <math.h>

#define T 16
#define A 8
#define H 128
#define E 32
#define G (4*H)   // 512 gate rows per LSTM

// d_ws layout (bytes) — images PRE-PERMUTED for kernel2's thread mapping
// (thread k <-> weight row r(k) = (k&3)*128 + (k>>2)):
//   [0, 128K)       W_hh_a f16 chunk-major: h8t at (c*512 + k)*16 = row r(k), chunk c
//   [128K, 256K)    W_hh_c same
//   [256K, 272K)    accx_a f16 at (t*512 + k)*2 = bias+W_ih@x(t) for row r(k)
//   [272K, 288K)    accx_c same
#define WS_WHH(L)   ((size_t)(L) * 131072u)
#define WS_ACCX(L)  (262144u + (size_t)(L) * 16384u)

typedef _Float16 h2t __attribute__((ext_vector_type(2)));
typedef _Float16 h8t __attribute__((ext_vector_type(8)));

__device__ __forceinline__ float sigmoidf_(float x) {
    return 1.0f / (1.0f + __expf(-x));               // safe at both extremes
}
__device__ __forceinline__ float tanhf_(float x) {
    return 1.0f - 2.0f / (1.0f + __expf(2.0f * x));  // safe at both extremes
}

#if __has_builtin(__builtin_amdgcn_fdot2)
#define DOT2(a, b, c) __builtin_amdgcn_fdot2((a), (b), (c), false)
#else
__device__ __forceinline__ float dot2_fb(h2t a, h2t b, float c) {
    return fmaf((float)a[0], (float)b[0], fmaf((float)a[1], (float)b[1], c));
}
#define DOT2(a, b, c) dot2_fb((a), (b), (c))
#endif

#define RPT16(M) M(0) M(1) M(2) M(3) M(4) M(5) M(6) M(7) \
                 M(8) M(9) M(10) M(11) M(12) M(13) M(14) M(15)
#define RPT8(M)  M(0) M(1) M(2) M(3) M(4) M(5) M(6) M(7)

// ---------------- kernel 1: whole-GPU prologue (cold fetch + convert) -------
__global__ __launch_bounds__(256)
void ppo_prep_kernel(const int* __restrict__ old_actions,
                     const float* __restrict__ init_input,
                     const float* __restrict__ W_ih_a, const float* __restrict__ W_hh_a,
                     const float* __restrict__ b_ih_a, const float* __restrict__ b_hh_a,
                     const float* __restrict__ W_ih_c, const float* __restrict__ W_hh_c,
                     const float* __restrict__ b_ih_c, const float* __restrict__ b_hh_c,
                     const float* __restrict__ embed,
                     char* __restrict__ ws)
{
    const int b = blockIdx.x;
    if (b < 64) {
        // ---- W_hh f32 -> f16, chunk-major, PERMUTED slot k <- row r(k) ----
        int tau  = b * 256 + threadIdx.x;       // [0, 16384)
        int lstm = tau >> 13;
        int i    = tau & 8191;
        int k    = i >> 4;                      // kernel2 thread slot 0..511
        int c    = i & 15;                      // chunk 0..15 (8 f32 each)
        int r    = ((k & 3) << 7) | (k >> 2);   // row this slot consumes
        const float* W = (lstm == 0) ? W_hh_a : W_hh_c;
        const float* src = W + r * H + c * 8;   // c fast across lanes: coalesced
        float4 fa = *(const float4*)(src);
        float4 fb = *(const float4*)(src + 4);
        h8t p = { (_Float16)fa.x, (_Float16)fa.y, (_Float16)fa.z, (_Float16)fa.w,
                  (_Float16)fb.x, (_Float16)fb.y, (_Float16)fb.z, (_Float16)fb.w };
        *(h8t*)(ws + WS_WHH(lstm) + (size_t)(c * 512 + k) * 16u) = p;
    } else {
        // ---- accx: slot (t,k) <- bias + W_ih[r(k),:] @ x(t), f16 ----
        int tau  = (b - 64) * 256 + threadIdx.x;   // [0, 16384)
        int lstm = tau >> 13;
        int i    = tau & 8191;
        int t    = i >> 9;                      // step 0..15
        int k    = i & 511;                     // slot 0..511
        int r    = ((k & 3) << 7) | (k >> 2);
        const float* W_ih = (lstm == 0) ? W_ih_a : W_ih_c;
        const float* b_ih = (lstm == 0) ? b_ih_a : b_ih_c;
        const float* b_hh = (lstm == 0) ? b_hh_a : b_hh_c;
        const float* xp = (t == 0) ? init_input
                                   : embed + ((t - 1) * A + old_actions[t - 1]) * E;
        const float* wr = W_ih + r * E;
        float s0 = 0.f, s1 = 0.f, s2 = 0.f, s3 = 0.f;
        #pragma unroll
        for (int e = 0; e < E; e += 4) {
            float4 wv = *(const float4*)(wr + e);
            float4 xv = *(const float4*)(xp + e);
            s0 = fmaf(wv.x, xv.x, s0); s1 = fmaf(wv.y, xv.y, s1);
            s2 = fmaf(wv.z, xv.z, s2); s3 = fmaf(wv.w, xv.w, s3);
        }
        float acc = b_ih[r] + b_hh[r] + ((s0 + s1) + (s2 + s3));
        *(_Float16*)(ws + WS_ACCX(lstm) + (size_t)(t * 512 + k) * 2u) = (_Float16)acc;
    }
}

// ---------------- kernel 2: serial recurrence, ONE barrier/step -------------
// Thread k: gate g=k&3 of unit j=k>>2. After the dot, the unit's 4 gates sit
// in adjacent lanes: 3 shfl_xor exchange, activation redundant in 4 lanes.
// h ping-pong: read hbuf[t&1], write hbuf[(t&1)^1] -> race-free with 1 barrier.
__global__ __attribute__((amdgpu_flat_work_group_size(512, 512),
                          amdgpu_waves_per_eu(2, 2)))
void ppo_ctrl_kernel(const int* __restrict__ old_actions,
                     const float* __restrict__ heads_W, const float* __restrict__ heads_b,
                     const float* __restrict__ critic_W, const float* __restrict__ critic_b,
                     const char* __restrict__ ws,
                     float* __restrict__ out)
{
    const int tid  = threadIdx.x;
    const int lane = tid & 63;
    const int wv   = tid >> 6;          // 8 waves
    const int lstm = blockIdx.x;        // 0 = actor, 1 = critic
    const bool actor = (lstm == 0);

    const int j = tid >> 2;             // hidden unit 0..127
    const int g = tid & 3;              // gate 0..3 (i,f,g,o)

    __shared__ __align__(16) _Float16 accx16[T * 512];  // 16 KB = 1024 h8t
    __shared__ __align__(16) _Float16 hbuf[2][H];       // 512 B ping-pong
    __shared__ __align__(16) _Float16 hhist[T][H];      // 4 KB

    // ---- stage accx to LDS: EXACTLY 1024 h8t (16 KB) — 2 per thread.
    // (R14 bug: copied 4 per thread = 32 KB, overrunning accx16 into
    //  hbuf/hhist and reading past the f16 accx region.)
    {
        const h8t* asrc = (const h8t*)(ws + WS_ACCX(lstm));
        h8t aa0 = asrc[tid];
        h8t aa1 = asrc[512 + tid];
        ((h8t*)accx16)[tid]       = aa0;
        ((h8t*)accx16)[512 + tid] = aa1;
    }

    // ---- W_hh slot -> 16 pinned h8t regs (fully linear/coalesced) ----
    const char* wbase = ws + WS_WHH(lstm);
#define LOADW(i) h8t w##i = *(const h8t*)(wbase + (size_t)((i) * 512 + tid) * 16u); \
        asm volatile("" : "+v"(w##i));
    RPT16(LOADW)
#undef LOADW

    // ---- heads prefetch (pinned; consumed after the loop; hides cold fetch) ----
    const int tt0 = wv, tt1 = wv + 8;
#define HWLOAD(a) \
    float hl0##a = heads_W[(tt0 * A + (a)) * H + lane]; \
    float hh0##a = heads_W[(tt0 * A + (a)) * H + 64 + lane]; \
    float hl1##a = heads_W[(tt1 * A + (a)) * H + lane]; \
    float hh1##a = heads_W[(tt1 * A + (a)) * H + 64 + lane]; \
    asm volatile("" : "+v"(hl0##a), "+v"(hh0##a), "+v"(hl1##a), "+v"(hh1##a));
    RPT8(HWLOAD)
#undef HWLOAD
    float hbv0 = heads_b[tt0 * A + (lane & 7)];
    float hbv1 = heads_b[tt1 * A + (lane & 7)];
    float cw0 = critic_W[lane], cw1 = critic_W[64 + lane], cb = critic_b[0];
    int act0 = old_actions[tt0], act1 = old_actions[tt1];
    asm volatile("" : "+v"(hbv0), "+v"(hbv1), "+v"(cw0), "+v"(cw1), "+v"(cb));

    __syncthreads();    // accx16 staged

    float c_reg = 0.0f;                 // cell state, replicated per 4-lane group
    const bool b0 = (g & 1) != 0, b1 = (g & 2) != 0;

    // ---- 16 sequential steps; ONE barrier per step ----
    #pragma unroll 1
    for (int t = 0; t < T; ++t) {
        float p = (float)accx16[t * 512 + tid];
        if (t != 0) {                   // t==0: h==0 -> dot is zero
            const h8t* hv = (const h8t*)hbuf[t & 1];
            float a0 = 0.f, a1 = 0.f, a2 = 0.f, a3 = 0.f;
#define MACC(i) { h8t hq = hv[i];                                          \
            a0 = DOT2(__builtin_shufflevector(w##i, w##i, 0, 1),           \
                      __builtin_shufflevector(hq,  hq,  0, 1), a0);        \
            a1 = DOT2(__builtin_shufflevector(w##i, w##i, 2, 3),           \
                      __builtin_shufflevector(hq,  hq,  2, 3), a1);        \
            a2 = DOT2(__builtin_shufflevector(w##i, w##i, 4, 5),           \
                      __builtin_shufflevector(hq,  hq,  4, 5), a2);        \
            a3 = DOT2(__builtin_shufflevector(w##i, w##i, 6, 7),           \
                      __builtin_shufflevector(hq,  hq,  6, 7), a3); }
            RPT16(MACC)
#undef MACC
            p += ((a0 + a1) + (a2 + a3));
        }

        // exchange the 4 gates within the 4-lane group (no LDS, no extra barrier)
        float q1 = __shfl_xor(p, 1);
        float q2 = __shfl_xor(p, 2);
        float q3 = __shfl_xor(q1, 2);
        // lane g holds: p=gate g, q1=gate g^1, q2=gate g^2, q3=gate g^3
        float gi = b1 ? (b0 ? q3 : q2) : (b0 ? q1 : p);
        float gf = b1 ? (b0 ? q2 : q3) : (b0 ? p  : q1);
        float gg = b1 ? (b0 ? q1 : p ) : (b0 ? q3 : q2);
        float go = b1 ? (b0 ? p  : q1) : (b0 ? q2 : q3);

        float cn = sigmoidf_(gf) * c_reg + sigmoidf_(gi) * tanhf_(gg);
        c_reg = cn;
        float hvv = sigmoidf_(go) * tanhf_(cn);
        _Float16 hf = (_Float16)hvv;
        if (g == 0) {                   // one writer per unit, into the OTHER buffer
            hbuf[(t & 1) ^ 1][j] = hf;
            hhist[t][j] = hf;
        }
        __syncthreads();
    }

    // ---- heads epilogue: zero global loads ----
    if (actor) {
#define LOGIT(rep,a,dst) {                                                \
        float pp = fmaf(hl##rep##a, hA, hh##rep##a * hB);                 \
        pp += __shfl_xor(pp, 1);  pp += __shfl_xor(pp, 2);                \
        pp += __shfl_xor(pp, 4);  pp += __shfl_xor(pp, 8);                \
        pp += __shfl_xor(pp, 16); pp += __shfl_xor(pp, 32);               \
        dst = pp + __shfl(hbv##rep, (a)); }
#define HEADS(rep) {                                                      \
        const int tt = tt##rep;                                           \
        float hA = (float)hhist[tt][lane];                                \
        float hB = (float)hhist[tt][64 + lane];                           \
        float l0,l1,l2,l3,l4,l5,l6,l7;                                    \
        LOGIT(rep,0,l0) LOGIT(rep,1,l1) LOGIT(rep,2,l2) LOGIT(rep,3,l3)   \
        LOGIT(rep,4,l4) LOGIT(rep,5,l5) LOGIT(rep,6,l6) LOGIT(rep,7,l7)   \
        if (lane == 0) {                                                  \
            float m = fmaxf(fmaxf(fmaxf(l0, l1), fmaxf(l2, l3)),          \
                            fmaxf(fmaxf(l4, l5), fmaxf(l6, l7)));         \
            float e0 = __expf(l0 - m), e1 = __expf(l1 - m),               \
                  e2 = __expf(l2 - m), e3 = __expf(l3 - m),               \
                  e4 = __expf(l4 - m), e5 = __expf(l5 - m),               \
                  e6 = __expf(l6 - m), e7 = __expf(l7 - m);               \
            float s = ((e0 + e1) + (e2 + e3)) + ((e4 + e5) + (e6 + e7));  \
            float logZ = m + __logf(s);                                   \
            int act = act##rep;                                           \
            float la = (act == 0) ? l0 : (act == 1) ? l1 : (act == 2) ? l2 : \
                       (act == 3) ? l3 : (act == 4) ? l4 : (act == 5) ? l5 : \
                       (act == 6) ? l6 : l7;                              \
            out[tt] = la - logZ;                                          \
            float w_ = e0*(l0-logZ) + e1*(l1-logZ) + e2*(l2-logZ) + e3*(l3-logZ) \
                     + e4*(l4-logZ) + e5*(l5-logZ) + e6*(l6-logZ) + e7*(l7-logZ); \
            out[T + tt] = -w_ / s;                                        \
        } }
        HEADS(0)
        HEADS(1)
#undef HEADS
#undef LOGIT
    } else {
        #pragma unroll
        for (int rep = 0; rep < 2; ++rep) {
            const int tt = (rep == 0) ? tt0 : tt1;
            float hA = (float)hhist[tt][lane];
            float hB = (float)hhist[tt][64 + lane];
            float p = fmaf(cw0, hA, cw1 * hB);
            p += __shfl_xor(p, 1);  p += __shfl_xor(p, 2);
            p += __shfl_xor(p, 4);  p += __shfl_xor(p, 8);
            p += __shfl_xor(p, 16); p += __shfl_xor(p, 32);
            if (lane == 0) out[2 * T + tt] = p + cb;   // values
        }
    }
}

extern "C" void kernel_launch(void* const* d_in, const int* in_sizes, int n_in,
                              void* d_out, int out_size, void* d_ws, size_t ws_size,
                              hipStream_t stream) {
    const int*   old_actions = (const int*)  d_in[0];
    const float* init_input  = (const float*)d_in[1];
    const float* W_ih_a      = (const float*)d_in[2];
    const float* W_hh_a      = (const float*)d_in[3];
    const float* b_ih_a      = (const float*)d_in[4];
    const float* b_hh_a      = (const float*)d_in[5];
    const float* heads_W     = (const float*)d_in[6];
    const float* heads_b     = (const float*)d_in[7];
    const float* W_ih_c      = (const float*)d_in[8];
    const float* W_hh_c      = (const float*)d_in[9];
    const float* b_ih_c      = (const float*)d_in[10];
    const float* b_hh_c      = (const float*)d_in[11];
    const float* critic_W    = (const float*)d_in[12];
    const float* critic_b    = (const float*)d_in[13];
    const float* embed       = (const float*)d_in[14];
    float* out = (float*)d_out;
    char* ws = (char*)d_ws;

    ppo_prep_kernel<<<dim3(128), dim3(256), 0, stream>>>(
        old_actions, init_input,
        W_ih_a, W_hh_a, b_ih_a, b_hh_a,
        W_ih_c, W_hh_c, b_ih_c, b_hh_c,
        embed, ws);

    ppo_ctrl_kernel<<<dim3(2), dim3(512), 0, stream>>>(
        old_actions, heads_W, heads_b, critic_W, critic_b, ws, out);
}

// Round 16
// 27.858 us; speedup vs baseline: 1.3767x; 1.1337x over previous
//
#include <hip/hip_runtime.h>
#include <math.h>

#define T 16
#define A 8
#define H 128
#define E 32
#define G (4*H)   // 512 gate rows per LSTM

// d_ws layout (bytes):
//   [0, 128K)          W_hh_a as f16, chunk-major: h8t at (c*512 + r)*16
//   [128K, 256K)       W_hh_c same
//   [256K, 272K)       accx_a f16 [t*512 + r]
//   [272K, 288K)       accx_c f16 [t*512 + r]
#define WS_WHH(L)   ((size_t)(L) * 131072u)
#define WS_ACCX(L)  (262144u + (size_t)(L) * 16384u)

typedef _Float16 h2t __attribute__((ext_vector_type(2)));
typedef _Float16 h8t __attribute__((ext_vector_type(8)));

__device__ __forceinline__ float sigmoidf_(float x) {
    return 1.0f / (1.0f + __expf(-x));               // safe at both extremes
}
__device__ __forceinline__ float tanhf_(float x) {
    return 1.0f - 2.0f / (1.0f + __expf(2.0f * x));  // safe at both extremes
}

#if __has_builtin(__builtin_amdgcn_fdot2)
#define DOT2(a, b, c) __builtin_amdgcn_fdot2((a), (b), (c), false)
#else
__device__ __forceinline__ float dot2_fb(h2t a, h2t b, float c) {
    return fmaf((float)a[0], (float)b[0], fmaf((float)a[1], (float)b[1], c));
}
#define DOT2(a, b, c) dot2_fb((a), (b), (c))
#endif

#define RPT16(M) M(0) M(1) M(2) M(3) M(4) M(5) M(6) M(7) \
                 M(8) M(9) M(10) M(11) M(12) M(13) M(14) M(15)

// ---------------- kernel 1: whole-GPU prologue (cold fetch + convert) -------
// blocks 0..63:   W_hh f32 -> f16 transpose-convert (one h8t chunk per thread)
// blocks 64..127: accx[t][r] = b_ih[r]+b_hh[r] + W_ih[r,:]@x(t)  (f16)
__global__ __launch_bounds__(256)
void ppo_prep_kernel(const int* __restrict__ old_actions,
                     const float* __restrict__ init_input,
                     const float* __restrict__ W_ih_a, const float* __restrict__ W_hh_a,
                     const float* __restrict__ b_ih_a, const float* __restrict__ b_hh_a,
                     const float* __restrict__ W_ih_c, const float* __restrict__ W_hh_c,
                     const float* __restrict__ b_ih_c, const float* __restrict__ b_hh_c,
                     const float* __restrict__ embed,
                     char* __restrict__ ws)
{
    const int b = blockIdx.x;
    if (b < 64) {
        // ---- convert: 16384 chunks total (2 LSTMs x 512 rows x 16 chunks) ----
        int tau  = b * 256 + threadIdx.x;       // [0, 16384)
        int lstm = tau >> 13;
        int i    = tau & 8191;
        int r    = i >> 4;                      // row 0..511
        int c    = i & 15;                      // chunk 0..15 (8 f32 each)
        const float* W = (lstm == 0) ? W_hh_a : W_hh_c;
        const float* src = W + r * H + c * 8;   // coalesced: c fast across lanes
        float4 fa = *(const float4*)(src);
        float4 fb = *(const float4*)(src + 4);
        h8t p = { (_Float16)fa.x, (_Float16)fa.y, (_Float16)fa.z, (_Float16)fa.w,
                  (_Float16)fb.x, (_Float16)fb.y, (_Float16)fb.z, (_Float16)fb.w };
        *(h8t*)(ws + WS_WHH(lstm) + (size_t)(c * 512 + r) * 16u) = p;
    } else {
        // ---- accx: 16384 dots (2 LSTMs x 16 steps x 512 rows) ----
        int tau  = (b - 64) * 256 + threadIdx.x;   // [0, 16384)
        int lstm = tau >> 13;
        int i    = tau & 8191;
        int t    = i >> 9;                      // step 0..15
        int r    = i & 511;                     // gate row 0..511
        const float* W_ih = (lstm == 0) ? W_ih_a : W_ih_c;
        const float* b_ih = (lstm == 0) ? b_ih_a : b_ih_c;
        const float* b_hh = (lstm == 0) ? b_hh_a : b_hh_c;
        const float* xp = (t == 0) ? init_input
                                   : embed + ((t - 1) * A + old_actions[t - 1]) * E;
        const float* wr = W_ih + r * E;
        float s0 = 0.f, s1 = 0.f, s2 = 0.f, s3 = 0.f;
        #pragma unroll
        for (int e = 0; e < E; e += 4) {
            float4 wv = *(const float4*)(wr + e);
            float4 xv = *(const float4*)(xp + e);
            s0 = fmaf(wv.x, xv.x, s0); s1 = fmaf(wv.y, xv.y, s1);
            s2 = fmaf(wv.z, xv.z, s2); s3 = fmaf(wv.w, xv.w, s3);
        }
        float acc = b_ih[r] + b_hh[r] + ((s0 + s1) + (s2 + s3));
        *(_Float16*)(ws + WS_ACCX(lstm) + (size_t)(t * 512 + r) * 2u) = (_Float16)acc;
    }
}

// ---------------- kernel 2: the serial recurrence (2 blocks) ----------------
__global__ __attribute__((amdgpu_flat_work_group_size(512, 512),
                          amdgpu_waves_per_eu(2, 2)))
void ppo_ctrl_kernel(const int* __restrict__ old_actions,
                     const float* __restrict__ heads_W, const float* __restrict__ heads_b,
                     const float* __restrict__ critic_W, const float* __restrict__ critic_b,
                     const char* __restrict__ ws,
                     float* __restrict__ out)
{
    const int tid  = threadIdx.x;
    const int lane = tid & 63;
    const int wv   = tid >> 6;          // 8 waves
    const int lstm = blockIdx.x;        // 0 = actor, 1 = critic
    const bool actor = (lstm == 0);

    __shared__ __align__(16) float gates_s[G];       // 2 KB
    __shared__ __align__(16) _Float16 h16[H];        // 256 B
    __shared__ __align__(16) _Float16 hhist[T][H];   // 4 KB

    // ---- stage W_hh row (f16) -> 16 pinned h8t regs; fully coalesced ----
    const char* wbase = ws + WS_WHH(lstm);
#define LOADW(i) h8t w##i = *(const h8t*)(wbase + (size_t)((i) * 512 + tid) * 16u); \
        asm volatile("" : "+v"(w##i));
    RPT16(LOADW)
#undef LOADW

    const _Float16* accg = (const _Float16*)(ws + WS_ACCX(lstm));

    float c_reg = 0.0f;                      // cell state (threads 0..127)
    const h8t* hv = (const h8t*)h16;         // broadcast reads: conflict-free

    // ---- 16 sequential steps; zero weight traffic in the loop ----
    #pragma unroll 1
    for (int t = 0; t < T; ++t) {
        float axv = (float)accg[t * 512 + tid];   // issued early, L2/L3-warm
        float a0 = 0.f, a1 = 0.f, a2 = 0.f, a3 = 0.f;
        if (t != 0) {                        // t==0: h==0 -> dot is zero
#define MACC(i) { h8t hq = hv[i];                                          \
            a0 = DOT2(__builtin_shufflevector(w##i, w##i, 0, 1),           \
                      __builtin_shufflevector(hq,  hq,  0, 1), a0);        \
            a1 = DOT2(__builtin_shufflevector(w##i, w##i, 2, 3),           \
                      __builtin_shufflevector(hq,  hq,  2, 3), a1);        \
            a2 = DOT2(__builtin_shufflevector(w##i, w##i, 4, 5),           \
                      __builtin_shufflevector(hq,  hq,  4, 5), a2);        \
            a3 = DOT2(__builtin_shufflevector(w##i, w##i, 6, 7),           \
                      __builtin_shufflevector(hq,  hq,  6, 7), a3); }
            RPT16(MACC)
#undef MACC
        }
        gates_s[tid] = axv + ((a0 + a1) + (a2 + a3));
        __syncthreads();

        if (tid < H) {   // gate order i,f,g,o
            float gi = gates_s[tid],       gf = gates_s[tid + H];
            float gg = gates_s[tid + 2*H], go = gates_s[tid + 3*H];
            float cn = sigmoidf_(gf) * c_reg + sigmoidf_(gi) * tanhf_(gg);
            c_reg = cn;
            float hvv = sigmoidf_(go) * tanhf_(cn);
            _Float16 hf = (_Float16)hvv;
            h16[tid] = hf;
            hhist[t][tid] = hf;
        }
        __syncthreads();
    }

    // ---- heads: all 16 steps in parallel (off the serial path) ----
    if (actor) {
        #pragma unroll 1
        for (int tt = wv; tt < T; tt += 8) {       // wave wv -> t = wv, wv+8
            float hA = (float)hhist[tt][lane];
            float hB = (float)hhist[tt][64 + lane];
#define LOGIT(a) float l##a; {                                            \
            const float* hw = heads_W + ((tt) * A + (a)) * H;             \
            float p = fmaf(hw[lane], hA, hw[64 + lane] * hB);             \
            p += __shfl_xor(p, 1);  p += __shfl_xor(p, 2);                \
            p += __shfl_xor(p, 4);  p += __shfl_xor(p, 8);                \
            p += __shfl_xor(p, 16); p += __shfl_xor(p, 32);               \
            l##a = p + heads_b[(tt) * A + (a)]; }
            LOGIT(0) LOGIT(1) LOGIT(2) LOGIT(3)
            LOGIT(4) LOGIT(5) LOGIT(6) LOGIT(7)
#undef LOGIT
            if (lane == 0) {
                float m = fmaxf(fmaxf(fmaxf(l0, l1), fmaxf(l2, l3)),
                                fmaxf(fmaxf(l4, l5), fmaxf(l6, l7)));
                float e0 = __expf(l0 - m), e1 = __expf(l1 - m),
                      e2 = __expf(l2 - m), e3 = __expf(l3 - m),
                      e4 = __expf(l4 - m), e5 = __expf(l5 - m),
                      e6 = __expf(l6 - m), e7 = __expf(l7 - m);
                float s = ((e0 + e1) + (e2 + e3)) + ((e4 + e5) + (e6 + e7));
                float logZ = m + __logf(s);
                int act = old_actions[tt];
                float la = (act == 0) ? l0 : (act == 1) ? l1 : (act == 2) ? l2 :
                           (act == 3) ? l3 : (act == 4) ? l4 : (act == 5) ? l5 :
                           (act == 6) ? l6 : l7;
                out[tt] = la - logZ;                       // log_probs
                float w_ = e0*(l0-logZ) + e1*(l1-logZ) + e2*(l2-logZ) + e3*(l3-logZ)
                         + e4*(l4-logZ) + e5*(l5-logZ) + e6*(l6-logZ) + e7*(l7-logZ);
                out[T + tt] = -w_ / s;                     // entropies
            }
        }
    } else {
        #pragma unroll 1
        for (int tt = wv; tt < T; tt += 8) {
            float hA = (float)hhist[tt][lane];
            float hB = (float)hhist[tt][64 + lane];
            float p = fmaf(critic_W[lane], hA, critic_W[64 + lane] * hB);
            p += __shfl_xor(p, 1);  p += __shfl_xor(p, 2);
            p += __shfl_xor(p, 4);  p += __shfl_xor(p, 8);
            p += __shfl_xor(p, 16); p += __shfl_xor(p, 32);
            if (lane == 0) out[2 * T + tt] = p + critic_b[0];   // values
        }
    }
}

extern "C" void kernel_launch(void* const* d_in, const int* in_sizes, int n_in,
                              void* d_out, int out_size, void* d_ws, size_t ws_size,
                              hipStream_t stream) {
    const int*   old_actions = (const int*)  d_in[0];
    const float* init_input  = (const float*)d_in[1];
    const float* W_ih_a      = (const float*)d_in[2];
    const float* W_hh_a      = (const float*)d_in[3];
    const float* b_ih_a      = (const float*)d_in[4];
    const float* b_hh_a      = (const float*)d_in[5];
    const float* heads_W     = (const float*)d_in[6];
    const float* heads_b     = (const float*)d_in[7];
    const float* W_ih_c      = (const float*)d_in[8];
    const float* W_hh_c      = (const float*)d_in[9];
    const float* b_ih_c      = (const float*)d_in[10];
    const float* b_hh_c      = (const float*)d_in[11];
    const float* critic_W    = (const float*)d_in[12];
    const float* critic_b    = (const float*)d_in[13];
    const float* embed       = (const float*)d_in[14];
    float* out = (float*)d_out;
    char* ws = (char*)d_ws;

    ppo_prep_kernel<<<dim3(128), dim3(256), 0, stream>>>(
        old_actions, init_input,
        W_ih_a, W_hh_a, b_ih_a, b_hh_a,
        W_ih_c, W_hh_c, b_ih_c, b_hh_c,
        embed, ws);

    ppo_ctrl_kernel<<<dim3(2), dim3(512), 0, stream>>>(
        old_actions, heads_W, heads_b, critic_W, critic_b, ws, out);
}